// Round 2
// baseline (10575.278 us; speedup 1.0000x reference)
//
#include <hip/hip_runtime.h>

// NSAFlowLayer: B=32 flows of (P=16384, K=64), 50 iters:
//   Y' = 0.9*Y + 0.1*X0
//   S  = NS_invsqrt(Y'^T Y')      (8 coupled Newton-Schulz iters on 64x64)
//   Y  = relu(0.5*Y' + 0.5*Y'@S)
// Pipeline: k_init (Y=X0 + gram of X0), then 50x { k_ns ; k_fused }.
// k_fused applies iteration t AND accumulates the gram for iteration t+1.

#define BATCH 32
#define NP    16384
#define NK    64
#define NITER 50
#define NSIT  8
#define EPSC  1e-8f

#define BPB   16               // blocks per batch
#define RPB   (NP / BPB)       // 1024 rows per block
#define CH    64               // chunk rows staged in LDS
#define NCH   (RPB / CH)       // 16 chunks
#define NBLK  (BATCH * BPB)    // 512 blocks
#define NT    256              // threads per block

// D[a][b] += Aa * BV.b  (4x4 outer-product accumulate)
#define FMA16(D, A0, A1, A2, A3, BV) do {                                  \
  D[0][0] = fmaf(A0, BV.x, D[0][0]); D[0][1] = fmaf(A0, BV.y, D[0][1]);    \
  D[0][2] = fmaf(A0, BV.z, D[0][2]); D[0][3] = fmaf(A0, BV.w, D[0][3]);    \
  D[1][0] = fmaf(A1, BV.x, D[1][0]); D[1][1] = fmaf(A1, BV.y, D[1][1]);    \
  D[1][2] = fmaf(A1, BV.z, D[1][2]); D[1][3] = fmaf(A1, BV.w, D[1][3]);    \
  D[2][0] = fmaf(A2, BV.x, D[2][0]); D[2][1] = fmaf(A2, BV.y, D[2][1]);    \
  D[2][2] = fmaf(A2, BV.z, D[2][2]); D[2][3] = fmaf(A2, BV.w, D[2][3]);    \
  D[3][0] = fmaf(A3, BV.x, D[3][0]); D[3][1] = fmaf(A3, BV.y, D[3][1]);    \
  D[3][2] = fmaf(A3, BV.z, D[3][2]); D[3][3] = fmaf(A3, BV.w, D[3][3]);    \
} while (0)

__device__ __forceinline__ void gram_acc(const float (*sZ)[NK], int i0, int j0,
                                         float (&acc)[4][4]) {
#pragma unroll 4
  for (int r = 0; r < CH; ++r) {
    float4 zi = *(const float4*)&sZ[r][i0];   // broadcast within 16-lane groups
    float4 zj = *(const float4*)&sZ[r][j0];   // 2-way aliasing = free
    FMA16(acc, zi.x, zi.y, zi.z, zi.w, zj);
  }
}

// ---------------------------------------------------------------------------
// k_init: Y := X0 ; gram partials of Y'_0 (= X0 since gradient step is a no-op)
// ---------------------------------------------------------------------------
__global__ __launch_bounds__(NT, 2) void k_init(const float* __restrict__ X0,
                                                float* __restrict__ Y,
                                                float* __restrict__ partials) {
  __shared__ float sZ[CH][NK];
  const int tid = threadIdx.x, blk = blockIdx.x;
  const int b = blk >> 4, rb = blk & 15;
  const size_t base = ((size_t)b * NP + (size_t)rb * RPB) * NK;
  const float* __restrict__ x0 = X0 + base;
  float* __restrict__ y = Y + base;
  const int it = tid >> 4, jt = tid & 15;
  const int i0 = it * 4, j0 = jt * 4;
  float acc[4][4] = {{0.f}};

  for (int ch = 0; ch < NCH; ++ch) {
    const float* xo = x0 + ch * CH * NK;
    float* yo = y + ch * CH * NK;
#pragma unroll
    for (int q = 0; q < 4; ++q) {
      int fi = (q * NT + tid) * 4;           // coalesced float4
      float4 xv = *(const float4*)(xo + fi);
      *(float4*)(yo + fi) = xv;              // Y = X0
      int r = fi >> 6, c = fi & 63;
      *(float4*)&sZ[r][c] = xv;
    }
    __syncthreads();
    gram_acc(sZ, i0, j0, acc);
    __syncthreads();
  }
  float* p = partials + (size_t)blk * NK * NK;
#pragma unroll
  for (int a = 0; a < 4; ++a)
    *(float4*)(p + (i0 + a) * NK + j0) =
        make_float4(acc[a][0], acc[a][1], acc[a][2], acc[a][3]);
}

// ---------------------------------------------------------------------------
// k_ns: per batch, M = sum(partials); S = NS_invsqrt(M). One block per batch.
// ---------------------------------------------------------------------------
__global__ void k_ns(const float* __restrict__ partials, float* __restrict__ S) {
  __shared__ float sA[NK][68];   // NS "Y" (padded: stride 68 keeps 16B align, <=2-way)
  __shared__ float sB[NK][68];   // NS "Z"
  __shared__ float sT[NK][68];   // NS "T"
  __shared__ float sRed[16];

  const int tid = threadIdx.x, b = blockIdx.x;
  const int it = tid >> 4, jt = tid & 15;
  const int i0 = it * 4, j0 = jt * 4;

  // reduce 16 per-block partials -> M (each thread owns a 4x4 tile)
  float m[4][4] = {{0.f}};
  const float* pb = partials + (size_t)b * BPB * NK * NK;
#pragma unroll
  for (int p = 0; p < BPB; ++p) {
    const float* pp = pb + p * NK * NK;
#pragma unroll
    for (int a = 0; a < 4; ++a) {
      float4 v = *(const float4*)(pp + (i0 + a) * NK + j0);
      m[a][0] += v.x; m[a][1] += v.y; m[a][2] += v.z; m[a][3] += v.w;
    }
  }
  // trace
  if (it == jt) sRed[it] = m[0][0] + m[1][1] + m[2][2] + m[3][3];
  __syncthreads();
  float nrm = EPSC;
#pragma unroll
  for (int i = 0; i < 16; ++i) nrm += sRed[i];
  const float inv = 1.0f / nrm;

  // sA = M/nrm, sB = I
#pragma unroll
  for (int a = 0; a < 4; ++a)
#pragma unroll
    for (int c = 0; c < 4; ++c) {
      sA[i0 + a][j0 + c] = m[a][c] * inv;
      sB[i0 + a][j0 + c] = (i0 + a) == (j0 + c) ? 1.0f : 0.0f;
    }
  __syncthreads();

  for (int ns = 0; ns < NSIT; ++ns) {
    // T = 1.5 I - 0.5 * (Z @ Y)
    float d[4][4] = {{0.f}};
#pragma unroll 4
    for (int k = 0; k < NK; ++k) {
      float b0 = sB[i0 + 0][k], b1 = sB[i0 + 1][k];
      float b2 = sB[i0 + 2][k], b3 = sB[i0 + 3][k];
      float4 av = *(const float4*)&sA[k][j0];
      FMA16(d, b0, b1, b2, b3, av);
    }
    // writing sT doesn't conflict with sA/sB reads; sync only before reading sT
#pragma unroll
    for (int a = 0; a < 4; ++a)
#pragma unroll
      for (int c = 0; c < 4; ++c)
        sT[i0 + a][j0 + c] =
            (((i0 + a) == (j0 + c)) ? 1.5f : 0.0f) - 0.5f * d[a][c];
    __syncthreads();

    // Ynew = Y@T ; Znew = T@Z  (both from current LDS state)
    float r1[4][4] = {{0.f}}, r2[4][4] = {{0.f}};
#pragma unroll 4
    for (int k = 0; k < NK; ++k) {
      float y0 = sA[i0 + 0][k], y1 = sA[i0 + 1][k];
      float y2 = sA[i0 + 2][k], y3 = sA[i0 + 3][k];
      float4 tv = *(const float4*)&sT[k][j0];
      FMA16(r1, y0, y1, y2, y3, tv);
      float t0 = sT[i0 + 0][k], t1 = sT[i0 + 1][k];
      float t2 = sT[i0 + 2][k], t3 = sT[i0 + 3][k];
      float4 zv = *(const float4*)&sB[k][j0];
      FMA16(r2, t0, t1, t2, t3, zv);
    }
    __syncthreads();
#pragma unroll
    for (int a = 0; a < 4; ++a)
#pragma unroll
      for (int c = 0; c < 4; ++c) {
        sA[i0 + a][j0 + c] = r1[a][c];
        sB[i0 + a][j0 + c] = r2[a][c];
      }
    __syncthreads();
  }

  const float sc = 1.0f / sqrtf(nrm);
  float* Sb = S + (size_t)b * NK * NK;
#pragma unroll
  for (int a = 0; a < 4; ++a) {
    float4 v = make_float4(sB[i0 + a][j0 + 0] * sc, sB[i0 + a][j0 + 1] * sc,
                           sB[i0 + a][j0 + 2] * sc, sB[i0 + a][j0 + 3] * sc);
    *(float4*)(Sb + (i0 + a) * NK + j0) = v;
  }
}

// ---------------------------------------------------------------------------
// k_fused: Y' = 0.9Y + 0.1X0 ; Ynew = relu(0.5 Y' + 0.5 Y'@S) ; write Y.
// If !last: also accumulate gram of Z = 0.9 Ynew + 0.1 X0 (next iter's Y').
// ---------------------------------------------------------------------------
__global__ __launch_bounds__(NT, 2) void k_fused(const float* __restrict__ X0,
                                                 float* __restrict__ Y,
                                                 const float* __restrict__ S,
                                                 float* __restrict__ partials,
                                                 int last) {
  __shared__ float sS[NK][NK];        // 16 KB (B-operand: row-major, f4 reads)
  __shared__ float sYp[CH][NK + 1];   // padded -> conflict-free A-operand reads
  __shared__ float sZ[CH][NK];        // gram staging

  const int tid = threadIdx.x, blk = blockIdx.x;
  const int b = blk >> 4, rb = blk & 15;
  const size_t base = ((size_t)b * NP + (size_t)rb * RPB) * NK;
  const float* __restrict__ x0 = X0 + base;
  float* __restrict__ y = Y + base;

  { // load S for this batch
    const float4* Sb = (const float4*)(S + (size_t)b * NK * NK);
    float4* d = (float4*)sS;
    for (int i = tid; i < NK * NK / 4; i += NT) d[i] = Sb[i];
  }

  const int it = tid >> 4, jt = tid & 15;
  const int i0 = it * 4, j0 = jt * 4;
  float acc[4][4] = {{0.f}};
  __syncthreads();

  for (int ch = 0; ch < NCH; ++ch) {
    const float* xo = x0 + ch * CH * NK;
    float* yo = y + ch * CH * NK;

    // stage Y' chunk (coalesced float4 in, scalar stores due to +1 pad)
#pragma unroll
    for (int q = 0; q < 4; ++q) {
      int fi = (q * NT + tid) * 4;
      int r = fi >> 6, c = fi & 63;
      float4 yv = *(const float4*)(yo + fi);
      float4 xv = *(const float4*)(xo + fi);
      sYp[r][c + 0] = fmaf(0.9f, yv.x, 0.1f * xv.x);
      sYp[r][c + 1] = fmaf(0.9f, yv.y, 0.1f * xv.y);
      sYp[r][c + 2] = fmaf(0.9f, yv.z, 0.1f * xv.z);
      sYp[r][c + 3] = fmaf(0.9f, yv.w, 0.1f * xv.w);
    }
    __syncthreads();

    // dot[a][c] = (Y' @ S) tile
    float dot[4][4] = {{0.f}};
#pragma unroll 4
    for (int k = 0; k < NK; ++k) {
      float a0 = sYp[i0 + 0][k], a1 = sYp[i0 + 1][k];
      float a2 = sYp[i0 + 2][k], a3 = sYp[i0 + 3][k];
      float4 bv = *(const float4*)&sS[k][j0];
      FMA16(dot, a0, a1, a2, a3, bv);
    }

    // epilogue: Ynew = relu(0.5 Y' + 0.5 dot); write Y; stage Z for gram
#pragma unroll
    for (int a = 0; a < 4; ++a) {
      int r = i0 + a;
      float4 yn;
      yn.x = fmaxf(fmaf(0.5f, sYp[r][j0 + 0], 0.5f * dot[a][0]), 0.f);
      yn.y = fmaxf(fmaf(0.5f, sYp[r][j0 + 1], 0.5f * dot[a][1]), 0.f);
      yn.z = fmaxf(fmaf(0.5f, sYp[r][j0 + 2], 0.5f * dot[a][2]), 0.f);
      yn.w = fmaxf(fmaf(0.5f, sYp[r][j0 + 3], 0.5f * dot[a][3]), 0.f);
      *(float4*)(yo + r * NK + j0) = yn;
      if (!last) {
        float4 xv = *(const float4*)(xo + r * NK + j0);  // L1/L2-hot re-read
        float4 z;
        z.x = fmaf(0.9f, yn.x, 0.1f * xv.x);
        z.y = fmaf(0.9f, yn.y, 0.1f * xv.y);
        z.z = fmaf(0.9f, yn.z, 0.1f * xv.z);
        z.w = fmaf(0.9f, yn.w, 0.1f * xv.w);
        *(float4*)&sZ[r][j0] = z;
      }
    }
    __syncthreads();
    if (!last) gram_acc(sZ, i0, j0, acc);
    __syncthreads();
  }

  if (!last) {
    float* p = partials + (size_t)blk * NK * NK;
#pragma unroll
    for (int a = 0; a < 4; ++a)
      *(float4*)(p + (i0 + a) * NK + j0) =
          make_float4(acc[a][0], acc[a][1], acc[a][2], acc[a][3]);
  }
}

// ---------------------------------------------------------------------------
extern "C" void kernel_launch(void* const* d_in, const int* in_sizes, int n_in,
                              void* d_out, int out_size, void* d_ws,
                              size_t ws_size, hipStream_t stream) {
  (void)in_sizes; (void)n_in; (void)out_size; (void)ws_size;
  const float* X0 = (const float*)d_in[0];
  float* Y = (float*)d_out;                       // Y lives in d_out across iters
  float* partials = (float*)d_ws;                 // 512*4096 f32 = 8 MB
  float* S = partials + (size_t)NBLK * NK * NK;   // 32*4096 f32 = 0.5 MB

  k_init<<<NBLK, NT, 0, stream>>>(X0, Y, partials);
  for (int t = 0; t < NITER; ++t) {
    k_ns<<<BATCH, NT, 0, stream>>>(partials, S);
    k_fused<<<NBLK, NT, 0, stream>>>(X0, Y, S, partials, t == NITER - 1 ? 1 : 0);
  }
}

// Round 4
// 9876.934 us; speedup vs baseline: 1.0707x; 1.0707x over previous
//
#include <hip/hip_runtime.h>

// NSAFlowLayer: B=32 flows of (P=16384, K=64), 50 iters:
//   Y' = 0.9*Y + 0.1*X0 ; S = NS_invsqrt(Y'^T Y') ; Y = relu(0.5*Y' + 0.5*Y'@S)
// Pipeline: k_init (Y=X0 + gram of X0), then 50x { k_ns ; k_fused }.
// R2 -> R3: grid 512->1024 blocks (4/CU), LDS 48.5->33KB (sZ folded into sYp,
// stride 68), k_ns 512 threads + iter-0 shortcut. Runtime shift fallback on ws.

#define BATCH 32
#define NP    16384
#define NK    64
#define NITER 50
#define NSIT  8
#define EPSC  1e-8f
#define CH    64               // chunk rows staged in LDS
#define NT    256              // threads per block (k_init/k_fused)
#define NTNS  512              // threads per block (k_ns)
#define SP    68               // padded LDS stride: 16B-aligned, <=2-way banks

// D[a][b] += Aa * BV.b  (4x4 outer-product accumulate)
#define FMA16(D, A0, A1, A2, A3, BV) do {                                  \
  D[0][0] = fmaf(A0, BV.x, D[0][0]); D[0][1] = fmaf(A0, BV.y, D[0][1]);    \
  D[0][2] = fmaf(A0, BV.z, D[0][2]); D[0][3] = fmaf(A0, BV.w, D[0][3]);    \
  D[1][0] = fmaf(A1, BV.x, D[1][0]); D[1][1] = fmaf(A1, BV.y, D[1][1]);    \
  D[1][2] = fmaf(A1, BV.z, D[1][2]); D[1][3] = fmaf(A1, BV.w, D[1][3]);    \
  D[2][0] = fmaf(A2, BV.x, D[2][0]); D[2][1] = fmaf(A2, BV.y, D[2][1]);    \
  D[2][2] = fmaf(A2, BV.z, D[2][2]); D[2][3] = fmaf(A2, BV.w, D[2][3]);    \
  D[3][0] = fmaf(A3, BV.x, D[3][0]); D[3][1] = fmaf(A3, BV.y, D[3][1]);    \
  D[3][2] = fmaf(A3, BV.z, D[3][2]); D[3][3] = fmaf(A3, BV.w, D[3][3]);    \
} while (0)

// 2-row variant for k_ns 2x4 tiles
#define FMA8(D, A0, A1, BV) do {                                           \
  D[0][0] = fmaf(A0, BV.x, D[0][0]); D[0][1] = fmaf(A0, BV.y, D[0][1]);    \
  D[0][2] = fmaf(A0, BV.z, D[0][2]); D[0][3] = fmaf(A0, BV.w, D[0][3]);    \
  D[1][0] = fmaf(A1, BV.x, D[1][0]); D[1][1] = fmaf(A1, BV.y, D[1][1]);    \
  D[1][2] = fmaf(A1, BV.z, D[1][2]); D[1][3] = fmaf(A1, BV.w, D[1][3]);    \
} while (0)

__device__ __forceinline__ void gram_acc(const float (*sZ)[SP], int i0, int j0,
                                         float (&acc)[4][4]) {
#pragma unroll 4
  for (int r = 0; r < CH; ++r) {
    float4 zi = *(const float4*)&sZ[r][i0];   // broadcast in 16-lane groups
    float4 zj = *(const float4*)&sZ[r][j0];   // <=2-way aliasing = free
    FMA16(acc, zi.x, zi.y, zi.z, zi.w, zj);
  }
}

// ---------------------------------------------------------------------------
// k_init: Y := X0 ; gram partials of Y'_0 (= X0)
// ---------------------------------------------------------------------------
__global__ __launch_bounds__(NT, 4) void k_init(const float* __restrict__ X0,
                                                float* __restrict__ Y,
                                                float* __restrict__ partials,
                                                int shift) {
  __shared__ float sZ[CH][SP];
  const int tid = threadIdx.x, blk = blockIdx.x;
  const int bpb = 1 << shift;
  const int b = blk >> shift, rb = blk & (bpb - 1);
  const int rpb = NP >> shift, nch = rpb / CH;
  const size_t base = ((size_t)b * NP + (size_t)rb * rpb) * NK;
  const float* __restrict__ x0 = X0 + base;
  float* __restrict__ y = Y + base;
  const int it = tid >> 4, jt = tid & 15;
  const int i0 = it * 4, j0 = jt * 4;
  float acc[4][4] = {{0.f}};

  for (int ch = 0; ch < nch; ++ch) {
    const float* xo = x0 + ch * CH * NK;
    float* yo = y + ch * CH * NK;
#pragma unroll
    for (int q = 0; q < 4; ++q) {
      int fi = (q * NT + tid) * 4;           // coalesced float4
      float4 xv = *(const float4*)(xo + fi);
      *(float4*)(yo + fi) = xv;              // Y = X0
      int r = fi >> 6, c = fi & 63;
      *(float4*)&sZ[r][c] = xv;              // 16B-aligned (SP%4==0)
    }
    __syncthreads();
    gram_acc(sZ, i0, j0, acc);
    __syncthreads();
  }
  float* p = partials + (size_t)blk * NK * NK;
#pragma unroll
  for (int a = 0; a < 4; ++a)
    *(float4*)(p + (i0 + a) * NK + j0) =
        make_float4(acc[a][0], acc[a][1], acc[a][2], acc[a][3]);
}

// ---------------------------------------------------------------------------
// k_ns: per batch, M = sum(partials); S = NS_invsqrt(M). One block per batch,
// 512 threads (8 waves), each thread a 2x4 tile. NS iter 0: Z=I shortcut.
// ---------------------------------------------------------------------------
__global__ __launch_bounds__(NTNS, 2) void k_ns(const float* __restrict__ partials,
                                                float* __restrict__ S,
                                                int npart) {
  __shared__ float sA[NK][SP];   // NS "Y"
  __shared__ float sB[NK][SP];   // NS "Z"
  __shared__ float sT[NK][SP];   // NS "T"
  __shared__ float sRed[8];

  const int tid = threadIdx.x, b = blockIdx.x;
  const int it = tid >> 4, jt = tid & 15;   // it 0..31, jt 0..15
  const int i0 = it * 2, j0 = jt * 4;

  // reduce partials -> M (each thread a 2x4 tile)
  float m[2][4] = {{0.f}};
  const float* pb = partials + (size_t)b * npart * NK * NK;
#pragma unroll 4
  for (int p = 0; p < npart; ++p) {
    const float* pp = pb + p * NK * NK;
#pragma unroll
    for (int a = 0; a < 2; ++a) {
      float4 v = *(const float4*)(pp + (i0 + a) * NK + j0);
      m[a][0] += v.x; m[a][1] += v.y; m[a][2] += v.z; m[a][3] += v.w;
    }
  }
  // trace: per-thread diag partial -> wave shuffle reduce -> LDS -> broadcast
  float local = 0.f;
#pragma unroll
  for (int a = 0; a < 2; ++a)
#pragma unroll
    for (int c = 0; c < 4; ++c)
      if ((i0 + a) == (j0 + c)) local += m[a][c];
#pragma unroll
  for (int off = 32; off; off >>= 1) local += __shfl_down(local, off);
  if ((tid & 63) == 0) sRed[tid >> 6] = local;
  __syncthreads();
  float nrm = EPSC;
#pragma unroll
  for (int w = 0; w < 8; ++w) nrm += sRed[w];
  const float inv = 1.0f / nrm;

  // sA = M/nrm, sB = I
#pragma unroll
  for (int a = 0; a < 2; ++a)
#pragma unroll
    for (int c = 0; c < 4; ++c) {
      sA[i0 + a][j0 + c] = m[a][c] * inv;
      sB[i0 + a][j0 + c] = (i0 + a) == (j0 + c) ? 1.0f : 0.0f;
    }
  __syncthreads();

  // --- NS iter 0 (Z = I): T = 1.5I - 0.5*Y ; Ynew = Y@T ; Znew = T ---
  {
#pragma unroll
    for (int a = 0; a < 2; ++a)
#pragma unroll
      for (int c = 0; c < 4; ++c)
        sT[i0 + a][j0 + c] =
            (((i0 + a) == (j0 + c)) ? 1.5f : 0.0f) - 0.5f * sA[i0 + a][j0 + c];
    __syncthreads();
    float r1[2][4] = {{0.f}};
#pragma unroll 4
    for (int k = 0; k < NK; ++k) {
      float y0 = sA[i0 + 0][k], y1 = sA[i0 + 1][k];
      float4 tv = *(const float4*)&sT[k][j0];
      FMA8(r1, y0, y1, tv);
    }
    __syncthreads();
#pragma unroll
    for (int a = 0; a < 2; ++a)
#pragma unroll
      for (int c = 0; c < 4; ++c) {
        sA[i0 + a][j0 + c] = r1[a][c];
        sB[i0 + a][j0 + c] = sT[i0 + a][j0 + c];
      }
    __syncthreads();
  }

  // --- NS iters 1..7 ---
  for (int ns = 1; ns < NSIT; ++ns) {
    float d[2][4] = {{0.f}};
#pragma unroll 4
    for (int k = 0; k < NK; ++k) {
      float b0 = sB[i0 + 0][k], b1 = sB[i0 + 1][k];
      float4 av = *(const float4*)&sA[k][j0];
      FMA8(d, b0, b1, av);
    }
#pragma unroll
    for (int a = 0; a < 2; ++a)
#pragma unroll
      for (int c = 0; c < 4; ++c)
        sT[i0 + a][j0 + c] =
            (((i0 + a) == (j0 + c)) ? 1.5f : 0.0f) - 0.5f * d[a][c];
    __syncthreads();

    float r1[2][4] = {{0.f}}, r2[2][4] = {{0.f}};
#pragma unroll 4
    for (int k = 0; k < NK; ++k) {
      float y0 = sA[i0 + 0][k], y1 = sA[i0 + 1][k];
      float4 tv = *(const float4*)&sT[k][j0];
      FMA8(r1, y0, y1, tv);
      float t0 = sT[i0 + 0][k], t1 = sT[i0 + 1][k];
      float4 zv = *(const float4*)&sB[k][j0];
      FMA8(r2, t0, t1, zv);
    }
    __syncthreads();
#pragma unroll
    for (int a = 0; a < 2; ++a)
#pragma unroll
      for (int c = 0; c < 4; ++c) {
        sA[i0 + a][j0 + c] = r1[a][c];
        sB[i0 + a][j0 + c] = r2[a][c];
      }
    __syncthreads();
  }

  const float sc = 1.0f / sqrtf(nrm);
  float* Sb = S + (size_t)b * NK * NK;
#pragma unroll
  for (int a = 0; a < 2; ++a) {
    float4 v = make_float4(sB[i0 + a][j0 + 0] * sc, sB[i0 + a][j0 + 1] * sc,
                           sB[i0 + a][j0 + 2] * sc, sB[i0 + a][j0 + 3] * sc);
    *(float4*)(Sb + (i0 + a) * NK + j0) = v;
  }
}

// ---------------------------------------------------------------------------
// k_fused: Y' = 0.9Y + 0.1X0 ; Ynew = relu(0.5 Y' + 0.5 Y'@S) ; write Y.
// If !last: overwrite sYp in place with Z = 0.9 Ynew + 0.1 X0, accumulate gram.
// LDS = sS 16KB + sYp 17.4KB = 33.4KB -> 4 blocks/CU.
// ---------------------------------------------------------------------------
__global__ __launch_bounds__(NT, 4) void k_fused(const float* __restrict__ X0,
                                                 float* __restrict__ Y,
                                                 const float* __restrict__ S,
                                                 float* __restrict__ partials,
                                                 int last, int shift) {
  __shared__ float sS[NK][NK];     // B-operand (row-major, f4 reads, 2-way max)
  __shared__ float sYp[CH][SP];    // A-operand / Z staging (stride 68)

  const int tid = threadIdx.x, blk = blockIdx.x;
  const int bpb = 1 << shift;
  const int b = blk >> shift, rb = blk & (bpb - 1);
  const int rpb = NP >> shift, nch = rpb / CH;
  const size_t base = ((size_t)b * NP + (size_t)rb * rpb) * NK;
  const float* __restrict__ x0 = X0 + base;
  float* __restrict__ y = Y + base;

  { // load S for this batch
    const float4* Sb = (const float4*)(S + (size_t)b * NK * NK);
    float4* d = (float4*)sS;
    for (int i = tid; i < NK * NK / 4; i += NT) d[i] = Sb[i];
  }

  const int it = tid >> 4, jt = tid & 15;
  const int i0 = it * 4, j0 = jt * 4;
  float acc[4][4] = {{0.f}};
  __syncthreads();

  for (int ch = 0; ch < nch; ++ch) {
    const float* xo = x0 + ch * CH * NK;
    float* yo = y + ch * CH * NK;

    // stage Y' chunk (float4 in, float4 LDS store: SP keeps 16B alignment)
#pragma unroll
    for (int q = 0; q < 4; ++q) {
      int fi = (q * NT + tid) * 4;
      int r = fi >> 6, c = fi & 63;
      float4 yv = *(const float4*)(yo + fi);
      float4 xv = *(const float4*)(xo + fi);
      float4 yp;
      yp.x = fmaf(0.9f, yv.x, 0.1f * xv.x);
      yp.y = fmaf(0.9f, yv.y, 0.1f * xv.y);
      yp.z = fmaf(0.9f, yv.z, 0.1f * xv.z);
      yp.w = fmaf(0.9f, yv.w, 0.1f * xv.w);
      *(float4*)&sYp[r][c] = yp;
    }
    __syncthreads();

    // dot[a][c] = (Y' @ S) tile
    float dot[4][4] = {{0.f}};
#pragma unroll 4
    for (int k = 0; k < NK; ++k) {
      float a0 = sYp[i0 + 0][k], a1 = sYp[i0 + 1][k];
      float a2 = sYp[i0 + 2][k], a3 = sYp[i0 + 3][k];
      float4 bv = *(const float4*)&sS[k][j0];
      FMA16(dot, a0, a1, a2, a3, bv);
    }
    __syncthreads();   // everyone done reading sYp before in-place Z overwrite

    // epilogue: Ynew = relu(0.5 Y' + 0.5 dot); write Y; Z -> sYp in place
#pragma unroll
    for (int a = 0; a < 4; ++a) {
      int r = i0 + a;
      float4 ypv = *(const float4*)&sYp[r][j0];   // own tile only
      float4 yn;
      yn.x = fmaxf(fmaf(0.5f, ypv.x, 0.5f * dot[a][0]), 0.f);
      yn.y = fmaxf(fmaf(0.5f, ypv.y, 0.5f * dot[a][1]), 0.f);
      yn.z = fmaxf(fmaf(0.5f, ypv.z, 0.5f * dot[a][2]), 0.f);
      yn.w = fmaxf(fmaf(0.5f, ypv.w, 0.5f * dot[a][3]), 0.f);
      *(float4*)(yo + r * NK + j0) = yn;
      if (!last) {
        float4 xv = *(const float4*)(xo + r * NK + j0);  // L1-hot re-read
        float4 z;
        z.x = fmaf(0.9f, yn.x, 0.1f * xv.x);
        z.y = fmaf(0.9f, yn.y, 0.1f * xv.y);
        z.z = fmaf(0.9f, yn.z, 0.1f * xv.z);
        z.w = fmaf(0.9f, yn.w, 0.1f * xv.w);
        *(float4*)&sYp[r][j0] = z;                 // in place (own tile)
      }
    }
    __syncthreads();
    if (!last) gram_acc(sYp, i0, j0, acc);
    __syncthreads();   // before next chunk's staging overwrite
  }

  if (!last) {
    float* p = partials + (size_t)blk * NK * NK;
#pragma unroll
    for (int a = 0; a < 4; ++a)
      *(float4*)(p + (i0 + a) * NK + j0) =
          make_float4(acc[a][0], acc[a][1], acc[a][2], acc[a][3]);
  }
}

// ---------------------------------------------------------------------------
extern "C" void kernel_launch(void* const* d_in, const int* in_sizes, int n_in,
                              void* d_out, int out_size, void* d_ws,
                              size_t ws_size, hipStream_t stream) {
  (void)in_sizes; (void)n_in; (void)out_size;
  const float* X0 = (const float*)d_in[0];
  float* Y = (float*)d_out;

  // pick grid size by available scratch: shift=5 -> 1024 blocks, 16.8MB partials
  const size_t needed5 =
      ((size_t)(BATCH << 5) + BATCH) * NK * NK * sizeof(float);
  const int shift = (ws_size >= needed5) ? 5 : 4;
  const int nblk = BATCH << shift;

  float* partials = (float*)d_ws;
  float* S = partials + (size_t)nblk * NK * NK;

  k_init<<<nblk, NT, 0, stream>>>(X0, Y, partials, shift);
  for (int t = 0; t < NITER; ++t) {
    k_ns<<<BATCH, NTNS, 0, stream>>>(partials, S, 1 << shift);
    k_fused<<<nblk, NT, 0, stream>>>(X0, Y, S, partials,
                                     t == NITER - 1 ? 1 : 0, shift);
  }
}